// Round 3
// baseline (515.728 us; speedup 1.0000x reference)
//
#include <hip/hip_runtime.h>
#include <math.h>

#define BLOCK 256
#define WAVES_PER_BLOCK (BLOCK / 64)
#define ROWS_PER_WAVE 32   // one float4 chunk per lane; lane pairs share a row
#define ITERS 8
#define N_MOD 8
#define NEG_INF (-__builtin_inff())

// Branchless (value, weight) top-2 update; strict '>' keeps lower-index-first.
__device__ __forceinline__ void top2_update(float vj, float wj,
                                            float& b1, float& w1,
                                            float& b2, float& w2) {
    bool gt1 = vj > b1;
    bool gt2 = vj > b2;
    float nb2 = gt1 ? b1 : (gt2 ? vj : b2);
    float nw2 = gt1 ? w1 : (gt2 ? wj : w2);
    b1 = gt1 ? vj : b1;
    w1 = gt1 ? wj : w1;
    b2 = nb2;
    w2 = nw2;
}

__global__ __launch_bounds__(BLOCK) void wta_kernel(
    const float* __restrict__ x,
    const int*   __restrict__ mask,
    const float* __restrict__ W,
    float*       __restrict__ out,
    long B)
{
    const int lane = threadIdx.x & 63;
    const int wave = threadIdx.x >> 6;
    const int h    = lane & 1;               // 0 = front half (elems 0-3), 1 = back (4-7)
    const long gw  = (long)blockIdx.x * WAVES_PER_BLOCK + wave;

    // --- softmax(W): wave-uniform, pure VALU, hides under streaming loads ---
    float sw[N_MOD];
    #pragma unroll
    for (int j = 0; j < N_MOD; ++j) sw[j] = W[j];
    float m = sw[0];
    #pragma unroll
    for (int j = 1; j < N_MOD; ++j) m = fmaxf(m, sw[j]);
    float s = 0.0f;
    #pragma unroll
    for (int j = 0; j < N_MOD; ++j) { sw[j] = __expf(sw[j] - m); s += sw[j]; }
    float inv = 1.0f / s;
    #pragma unroll
    for (int j = 0; j < N_MOD; ++j) sw[j] *= inv;

    // weights for my half's 4 elements (h is per-lane-parity, branchless select)
    float wA = h ? sw[4] : sw[0];
    float wB = h ? sw[5] : sw[1];
    float wC = h ? sw[6] : sw[2];
    float wD = h ? sw[7] : sw[3];

    const float4* xv4 = (const float4*)x;
    const int4*   mv4 = (const int4*)mask;

    // depth-2 software pipeline over ITERS windows of 32 rows per wave
    long row0 = ((long)gw * ITERS + 0) * ROWS_PER_WAVE;
    float4 xv; int4 mv;
    bool valid0 = row0 < B;
    if (valid0) {
        long chunk = row0 * 2 + lane;          // float4 index; dense across lanes
        xv = xv4[chunk];
        mv = mv4[chunk];
    }

    #pragma unroll
    for (int k = 0; k < ITERS; ++k) {
        long rowk = ((long)gw * ITERS + k) * ROWS_PER_WAVE;
        bool validk = rowk < B;

        // prefetch next window (dense wave-load, 16 lines, 4 lanes/line)
        float4 nxv; int4 nmv;
        if (k + 1 < ITERS) {
            long rown = ((long)gw * ITERS + (k + 1)) * ROWS_PER_WAVE;
            if (rown < B) {
                long chunk = rown * 2 + lane;
                nxv = xv4[chunk];
                nmv = mv4[chunk];
            }
        }

        if (validk) {
            // masked values of my half
            float v0 = mv.x ? xv.x : NEG_INF;
            float v1 = mv.y ? xv.y : NEG_INF;
            float v2 = mv.z ? xv.z : NEG_INF;
            float v3 = mv.w ? xv.w : NEG_INF;

            // partial top-2 of my half (ascending index, strict '>')
            float b1 = NEG_INF, b2 = NEG_INF, w1 = 0.0f, w2 = 0.0f;
            top2_update(v0, wA, b1, w1, b2, w2);
            top2_update(v1, wB, b1, w1, b2, w2);
            top2_update(v2, wC, b1, w1, b2, w2);
            top2_update(v3, wD, b1, w1, b2, w2);

            // exchange partials with lane partner
            float ob1 = __shfl_xor(b1, 1);
            float ow1 = __shfl_xor(w1, 1);
            float ob2 = __shfl_xor(b2, 1);
            float ow2 = __shfl_xor(w2, 1);

            // f = front half's partial, kk = back half's partial
            float f1  = h ? ob1 : b1,  fw1 = h ? ow1 : w1;
            float f2  = h ? ob2 : b2,  fw2 = h ? ow2 : w2;
            float k1  = h ? b1  : ob1, kw1 = h ? w1  : ow1;
            float k2  = h ? b2  : ob2, kw2 = h ? w2  : ow2;

            // merge two sorted pairs; front (lower indices) wins ties
            bool kwin = k1 > f1;
            float t1  = kwin ? k1  : f1;
            float tw1 = kwin ? kw1 : fw1;
            // remaining candidates: one front value, one back value
            float fc  = kwin ? f1  : f2;
            float fcw = kwin ? fw1 : fw2;
            float kc  = kwin ? k2  : k1;
            float kcw = kwin ? kw2 : kw1;
            bool bwin = kc > fc;                 // back wins only if strictly greater
            float t2  = bwin ? kc  : fc;
            float tw2 = bwin ? kcw : fcw;

            float r = t1 * tw1 + t2 * tw2 + 0.5f * (t1 + t2);

            // even lane of each pair stores the row result (dense 128B per wave)
            if (h == 0) out[rowk + (lane >> 1)] = r;
        }

        xv = nxv;
        mv = nmv;
    }
}

extern "C" void kernel_launch(void* const* d_in, const int* in_sizes, int n_in,
                              void* d_out, int out_size, void* d_ws, size_t ws_size,
                              hipStream_t stream) {
    const float* x    = (const float*)d_in[0];
    const int*   mask = (const int*)d_in[1];
    const float* W    = (const float*)d_in[2];
    float*       out  = (float*)d_out;

    long B = out_size;  // 8388608 rows, one output per row
    long rows_per_block = (long)WAVES_PER_BLOCK * ITERS * ROWS_PER_WAVE;  // 1024
    int grid = (int)((B + rows_per_block - 1) / rows_per_block);          // 8192
    wta_kernel<<<grid, BLOCK, 0, stream>>>(x, mask, W, out, B);
}

// Round 4
// 494.652 us; speedup vs baseline: 1.0426x; 1.0426x over previous
//
#include <hip/hip_runtime.h>
#include <math.h>

#define BLOCK 256
#define N_MOD 8
#define NEG_INF (-__builtin_inff())

// ext_vector types so __builtin_nontemporal_load accepts them
typedef float vfloat4 __attribute__((ext_vector_type(4)));
typedef int   vint4   __attribute__((ext_vector_type(4)));

__global__ __launch_bounds__(BLOCK) void wta_kernel(
    const float* __restrict__ x,
    const int*   __restrict__ mask,
    const float* __restrict__ W,
    float*       __restrict__ out,
    int B)
{
    int b = blockIdx.x * BLOCK + threadIdx.x;
    if (b >= B) return;

    // --- nontemporal streaming loads: 32B x + 32B mask per row ---
    const vfloat4* xv = (const vfloat4*)(x + (size_t)b * N_MOD);
    vfloat4 xa = __builtin_nontemporal_load(xv);
    vfloat4 xb = __builtin_nontemporal_load(xv + 1);
    const vint4* mv = (const vint4*)(mask + (size_t)b * N_MOD);
    vint4 ma = __builtin_nontemporal_load(mv);
    vint4 mb = __builtin_nontemporal_load(mv + 1);

    // --- softmax(W): wave-uniform (scalarized), pure VALU, hides under loads ---
    float sw[N_MOD];
    #pragma unroll
    for (int j = 0; j < N_MOD; ++j) sw[j] = W[j];
    float m = sw[0];
    #pragma unroll
    for (int j = 1; j < N_MOD; ++j) m = fmaxf(m, sw[j]);
    float s = 0.0f;
    #pragma unroll
    for (int j = 0; j < N_MOD; ++j) { sw[j] = __expf(sw[j] - m); s += sw[j]; }
    float inv = 1.0f / s;
    #pragma unroll
    for (int j = 0; j < N_MOD; ++j) sw[j] *= inv;

    float v[N_MOD];
    v[0] = ma.x ? xa.x : NEG_INF;
    v[1] = ma.y ? xa.y : NEG_INF;
    v[2] = ma.z ? xa.z : NEG_INF;
    v[3] = ma.w ? xa.w : NEG_INF;
    v[4] = mb.x ? xb.x : NEG_INF;
    v[5] = mb.y ? xb.y : NEG_INF;
    v[6] = mb.z ? xb.z : NEG_INF;
    v[7] = mb.w ? xb.w : NEG_INF;

    // --- branchless top-2 carrying softmax weights; strict '>' preserves
    //     lax.top_k lower-index-first tie-breaking ---
    float b1 = NEG_INF, b2 = NEG_INF, w1 = 0.0f, w2 = 0.0f;
    #pragma unroll
    for (int j = 0; j < N_MOD; ++j) {
        float vj = v[j], wj = sw[j];
        bool gt1 = vj > b1;
        bool gt2 = vj > b2;
        float nb2 = gt1 ? b1 : (gt2 ? vj : b2);
        float nw2 = gt1 ? w1 : (gt2 ? wj : w2);
        b1 = gt1 ? vj : b1;
        w1 = gt1 ? wj : w1;
        b2 = nb2;
        w2 = nw2;
    }

    // out = v1*softW[i1] + v2*softW[i2] + mean(top2); nontemporal store
    __builtin_nontemporal_store(b1 * w1 + b2 * w2 + 0.5f * (b1 + b2), out + b);
}

extern "C" void kernel_launch(void* const* d_in, const int* in_sizes, int n_in,
                              void* d_out, int out_size, void* d_ws, size_t ws_size,
                              hipStream_t stream) {
    const float* x    = (const float*)d_in[0];
    const int*   mask = (const int*)d_in[1];
    const float* W    = (const float*)d_in[2];
    float*       out  = (float*)d_out;

    int B = out_size;  // 8388608 rows, one output per row
    int grid = (B + BLOCK - 1) / BLOCK;
    wta_kernel<<<grid, BLOCK, 0, stream>>>(x, mask, W, out, B);
}